// Round 7
// baseline (332.472 us; speedup 1.0000x reference)
//
#include <hip/hip_runtime.h>

#define N 256
#define C 128
#define H 4
#define D 32
#define NP (N*N)            // 65536 pairs
#define LN_EPS 1e-5f
#define LOG2E 1.4426950408889634f

using f32x4 = __attribute__((ext_vector_type(4))) float;
using bf8   = __attribute__((ext_vector_type(8))) short;   // 8 x bf16 (4 VGPRs)

__device__ __forceinline__ float bf2f(ushort u) {
    union { uint u; float f; } v; v.u = ((uint)u) << 16; return v.f;
}
__device__ __forceinline__ ushort f2bf(float f) {           // RNE
    union { float f; uint u; } v; v.f = f;
    uint u = v.u;
    u += 0x7fffu + ((u >> 16) & 1u);
    return (ushort)(u >> 16);
}
__device__ __forceinline__ ushort f2bf_trunc(float f) {     // truncate (1 VALU op)
    union { float f; uint u; } v; v.f = f;
    return (ushort)(v.u >> 16);
}

// ---------------------------------------------------------------- weights
// q-scale folds 1/sqrt(D) AND log2e (softmax uses exp2 directly)
__global__ __launch_bounds__(256) void prep_weights(
    const float* __restrict__ wq, const float* __restrict__ wk,
    const float* __restrict__ wv, const float* __restrict__ wg,
    const float* __restrict__ wb, const float* __restrict__ wo,
    ushort* __restrict__ Wcat, ushort* __restrict__ Wb, ushort* __restrict__ Wo)
{
    int t = blockIdx.x * 256 + threadIdx.x;    // 65536 threads
    const float scale = 0.17677669529663689f * LOG2E;
    float v;
    if (t < 16384)       v = wq[t] * scale;
    else if (t < 32768)  v = wk[t - 16384];
    else if (t < 49152)  v = wv[t - 32768];
    else                 v = wg[t - 49152];
    Wcat[t] = f2bf(v);
    if (t < 16384) Wo[t] = f2bf(wo[t]);
    if (t < 512)   Wb[t] = f2bf(wb[t]);
}

// ---------------------------------------------------------------- layernorm
__global__ __launch_bounds__(256) void ln_kernel(
    const float* __restrict__ x, const float* __restrict__ lnw,
    const float* __restrict__ lnb, ushort* __restrict__ xn)
{
    int wave = threadIdx.x >> 6, lane = threadIdx.x & 63;
    int p = blockIdx.x * 4 + wave;
    const float* xp = x + (size_t)p * C;
    float a0 = xp[lane], a1 = xp[lane + 64];
    float s = a0 + a1, ss = a0 * a0 + a1 * a1;
    #pragma unroll
    for (int m = 1; m < 64; m <<= 1) {
        s  += __shfl_xor(s, m, 64);
        ss += __shfl_xor(ss, m, 64);
    }
    float mean = s * (1.f / 128.f);
    float var  = ss * (1.f / 128.f) - mean * mean;
    float rstd = rsqrtf(var + LN_EPS);
    ushort* op = xn + (size_t)p * C;
    op[lane]      = f2bf((a0 - mean) * rstd * lnw[lane]      + lnb[lane]);
    op[lane + 64] = f2bf((a1 - mean) * rstd * lnw[lane + 64] + lnb[lane + 64]);
}

// ---------------------------------------------------------------- triangle bias
// Output: bf16 * LOG2E, pre-permuted into the attn fragment layout:
//   (h,q,k): qc=q>>4, quad=(q>>2)&3, r=q&3, n=k>>4, lrow=k&15
//   lane=quad*16+lrow, v=n*4+r, j=v>>3, m=v&7
//   idx = h*65536 + (((qc*8 + j)*64 + lane)*8 + m)
__global__ __launch_bounds__(256) void tri_kernel(
    const ushort* __restrict__ xn, const ushort* __restrict__ Wb,
    ushort* __restrict__ tri_p)
{
    __shared__ float wb[512];
    int t = threadIdx.x;
    wb[t]       = bf2f(Wb[t]);
    wb[t + 256] = bf2f(Wb[t + 256]);
    __syncthreads();
    int p = blockIdx.x * 256 + t;
    const ushort* xp = xn + (size_t)p * C;
    float acc0 = 0, acc1 = 0, acc2 = 0, acc3 = 0;
    #pragma unroll
    for (int c8 = 0; c8 < 16; c8++) {
        uint4 pk = ((const uint4*)xp)[c8];
        const ushort* u = (const ushort*)&pk;
        #pragma unroll
        for (int j = 0; j < 8; j++) {
            float xv = bf2f(u[j]);
            int c = c8 * 8 + j;
            acc0 += xv * wb[c];
            acc1 += xv * wb[128 + c];
            acc2 += xv * wb[256 + c];
            acc3 += xv * wb[384 + c];
        }
    }
    int q = p >> 8, k = p & 255;
    int qc = q >> 4, quad = (q >> 2) & 3, r = q & 3;
    int n = k >> 4, lrow = k & 15;
    int lane = quad * 16 + lrow;
    int v = n * 4 + r, j = v >> 3, m = v & 7;
    int base = ((qc * 8 + j) * 64 + lane) * 8 + m;
    tri_p[base]             = f2bf(acc0 * LOG2E);
    tri_p[65536 + base]     = f2bf(acc1 * LOG2E);
    tri_p[2 * 65536 + base] = f2bf(acc2 * LOG2E);
    tri_p[3 * 65536 + base] = f2bf(acc3 * LOG2E);
}

// ---------------------------------------------------------------- fused proj+attn+gate+out
// grid (i=256, jq=4), 256 threads = 4 waves. Wave w owns q-chunk qc=jq*4+w and
// produces K/V for key-tiles {w,w+4,w+8,w+12} (covers all 16 across 4 waves;
// the wave's own Q/gate tile tt==jq is among them). LDS 52 KB -> 3 blocks/CU,
// 12 waves/CU. All fragment layouts verbatim from verified rounds 5/6.
__global__ __launch_bounds__(256, 3) void fused_attn(
    const ushort* __restrict__ xn, const ushort* __restrict__ Wcat,
    const float* __restrict__ bg, const ushort* __restrict__ Wo,
    const float* __restrict__ bo, const ushort* __restrict__ tri_p,
    const float* __restrict__ mask, float* __restrict__ out)
{
    __shared__ ushort Kf[8192];       // 16 KB  K frags, chunk c = tile*64+lane
    __shared__ ushort Vf[8192];       // 16 KB  V^T frags, d-major, xor-swizzled
    __shared__ ushort Qf[2048];       //  4 KB  per-wave Q frags (own qc)
    __shared__ ushort Pf[4][2048];    // 16 KB  per-wave P / gated-O frags

    int i  = blockIdx.x;
    int jq = blockIdx.y;
    int t  = threadIdx.x;
    int wave = t >> 6, lane = t & 63;
    int lrow = lane & 15, quad = lane >> 4;
    int qc = jq * 4 + wave;            // this wave's q-chunk (0..15)

    // mask bias per lane's 16 key-columns (log2e-folded)
    float mb[16];
    #pragma unroll
    for (int n = 0; n < 16; n++)
        mb[n] = (1e9f * LOG2E) * (mask[i * N + n * 16 + lrow] - 1.0f);

    const ushort* xrow = xn + (size_t)(i * N) * C;
    ushort* Pw = &Pf[wave][0];
    int pq = quad * 32 + (lrow & 7);
    int l3 = (lrow >> 3) & 1;

    f32x4 outacc[8];
    #pragma unroll
    for (int n8 = 0; n8 < 8; n8++) outacc[n8] = (f32x4){0.f, 0.f, 0.f, 0.f};

    #pragma unroll 1
    for (int h = 0; h < H; h++) {
        const ushort* trih = tri_p + (size_t)h * 65536;
        bf8 xq[4];
        // ---------- K/V projection into frag-ordered LDS ----------
        {
            const ushort* WkB = Wcat + (size_t)(128 + h * D) * C + quad * 8;
            const ushort* WvB = Wcat + (size_t)(256 + h * D) * C + quad * 8;
            bf8 aK[2][4];
            #pragma unroll
            for (int ks = 0; ks < 4; ks++)
                #pragma unroll
                for (int mm = 0; mm < 2; mm++)
                    aK[mm][ks] = *(const bf8*)(WkB + (size_t)(mm * 16 + lrow) * C + ks * 32);

            #pragma unroll
            for (int tt = 0; tt < 4; tt++) {
                int tile = tt * 4 + wave;
                bf8 xfr[4];
                #pragma unroll
                for (int ks = 0; ks < 4; ks++)
                    xfr[ks] = *(const bf8*)(xrow + (size_t)(tile * 16 + lrow) * C + ks * 32 + quad * 8);
                if (tt == jq) {
                    #pragma unroll
                    for (int ks = 0; ks < 4; ks++) xq[ks] = xfr[ks];
                }
                f32x4 accK[2], accV[2];
                #pragma unroll
                for (int mm = 0; mm < 2; mm++) {
                    accK[mm] = (f32x4){0.f, 0.f, 0.f, 0.f};
                    accV[mm] = (f32x4){0.f, 0.f, 0.f, 0.f};
                }
                #pragma unroll
                for (int ks = 0; ks < 4; ks++) {
                    #pragma unroll
                    for (int mm = 0; mm < 2; mm++) {
                        bf8 bV = *(const bf8*)(WvB + (size_t)(mm * 16 + lrow) * C + ks * 32);
                        accK[mm] = __builtin_amdgcn_mfma_f32_16x16x32_bf16(aK[mm][ks], xfr[ks], accK[mm], 0, 0, 0);
                        accV[mm] = __builtin_amdgcn_mfma_f32_16x16x32_bf16(xfr[ks], bV, accV[mm], 0, 0, 0);
                    }
                }
                #pragma unroll
                for (int mm = 0; mm < 2; mm++) {
                    ushort4 pk;
                    pk.x = f2bf(accK[mm][0]); pk.y = f2bf(accK[mm][1]);
                    pk.z = f2bf(accK[mm][2]); pk.w = f2bf(accK[mm][3]);
                    *(ushort4*)&Kf[tile * 512 + (mm * 2 + (quad >> 1)) * 128 + lrow * 8 + (quad & 1) * 4] = pk;
                    int d = mm * 16 + lrow;
                    pk.x = f2bf(accV[mm][0]); pk.y = f2bf(accV[mm][1]);
                    pk.z = f2bf(accV[mm][2]); pk.w = f2bf(accV[mm][3]);
                    *(ushort4*)&Vf[(d * 32 + ((tile * 2 + (quad >> 1)) ^ (lrow & 7))) * 8 + (quad & 1) * 4] = pk;
                }
            }
            // ---- Q proj for own tile (uses xq) ----
            const ushort* WqB = Wcat + (size_t)(h * D) * C + quad * 8;
            f32x4 accQ[2];
            accQ[0] = (f32x4){0.f, 0.f, 0.f, 0.f};
            accQ[1] = (f32x4){0.f, 0.f, 0.f, 0.f};
            #pragma unroll
            for (int ks = 0; ks < 4; ks++)
                #pragma unroll
                for (int mm = 0; mm < 2; mm++) {
                    bf8 aQ = *(const bf8*)(WqB + (size_t)(mm * 16 + lrow) * C + ks * 32);
                    accQ[mm] = __builtin_amdgcn_mfma_f32_16x16x32_bf16(aQ, xq[ks], accQ[mm], 0, 0, 0);
                }
            #pragma unroll
            for (int mm = 0; mm < 2; mm++) {
                ushort4 pk;
                pk.x = f2bf(accQ[mm][0]); pk.y = f2bf(accQ[mm][1]);
                pk.z = f2bf(accQ[mm][2]); pk.w = f2bf(accQ[mm][3]);
                *(ushort4*)&Qf[wave * 512 + (mm * 2 + (quad >> 1)) * 128 + lrow * 8 + (quad & 1) * 4] = pk;
            }
        }
        __syncthreads();

        // ---------- attention for qc ----------
        bf8 aq = *(const bf8*)&Qf[wave * 512 + quad * 128 + lrow * 8];
        float sum[4] = {0.f, 0.f, 0.f, 0.f};
        f32x4 o[2];
        o[0] = (f32x4){0.f, 0.f, 0.f, 0.f};
        o[1] = (f32x4){0.f, 0.f, 0.f, 0.f};

        #pragma unroll
        for (int hf = 0; hf < 2; hf++) {
            f32x4 s8[8];
            #pragma unroll
            for (int n8 = 0; n8 < 8; n8++) {
                bf8 kf = *(const bf8*)&Kf[(hf * 8 + n8) * 512 + quad * 128 + lrow * 8];
                s8[n8] = __builtin_amdgcn_mfma_f32_16x16x32_bf16(
                    aq, kf, (f32x4){0.f, 0.f, 0.f, 0.f}, 0, 0, 0);
            }
            const ushort* tp = trih + ((size_t)(qc * 8 + hf * 4) * 64 + lane) * 8;
            bf8 tf[4];
            #pragma unroll
            for (int jj = 0; jj < 4; jj++)
                tf[jj] = *(const bf8*)(tp + jj * 512);

            #pragma unroll
            for (int n8 = 0; n8 < 8; n8++) {
                int pa = (n8 >> 1) * 512 + (((n8 << 1) + l3) & 3) * 128 + pq;
                #pragma unroll
                for (int r = 0; r < 4; r++) {
                    float tb = bf2f(((const ushort*)&tf[n8 >> 1])[((n8 & 1) << 2) + r]);
                    float e  = exp2f(s8[n8][r] + tb + mb[hf * 8 + n8]);
                    sum[r]  += e;
                    Pw[pa + r * 8] = f2bf_trunc(e);
                }
            }
            __asm__ volatile("s_waitcnt lgkmcnt(0)" ::: "memory");

            #pragma unroll
            for (int ks = 0; ks < 4; ks++) {
                bf8 ap = *(const bf8*)&Pw[(ks * 64 + lane) * 8];
                int ksg = hf * 4 + ks;
                #pragma unroll
                for (int nv = 0; nv < 2; nv++) {
                    bf8 bv = *(const bf8*)&Vf[((nv * 16 + lrow) * 32 + ((ksg * 4 + quad) ^ (lrow & 7))) * 8];
                    o[nv] = __builtin_amdgcn_mfma_f32_16x16x32_bf16(ap, bv, o[nv], 0, 0, 0);
                }
            }
        }
        float inv[4];
        #pragma unroll
        for (int r = 0; r < 4; r++) {
            float s = sum[r];
            s += __shfl_xor(s, 1, 64);
            s += __shfl_xor(s, 2, 64);
            s += __shfl_xor(s, 4, 64);
            s += __shfl_xor(s, 8, 64);
            inv[r] = 1.f / s;
        }

        // ---------- gate (C/D layout == O layout) + gated-O -> A-frag + out-proj ----------
        {
            const ushort* WgB = Wcat + (size_t)(384 + h * D) * C + quad * 8;
            #pragma unroll
            for (int nv = 0; nv < 2; nv++) {
                f32x4 gacc = (f32x4){0.f, 0.f, 0.f, 0.f};
                #pragma unroll
                for (int ks = 0; ks < 4; ks++) {
                    bf8 gW = *(const bf8*)(WgB + (size_t)(nv * 16 + lrow) * C + ks * 32);
                    gacc = __builtin_amdgcn_mfma_f32_16x16x32_bf16(xq[ks], gW, gacc, 0, 0, 0);
                }
                float bgv = bg[h * D + nv * 16 + lrow];
                #pragma unroll
                for (int r = 0; r < 4; r++) {
                    float g  = 1.f / (1.f + __expf(-(gacc[r] + bgv)));
                    float og = o[nv][r] * inv[r] * g;
                    Pw[(nv * 2 + (lrow >> 3)) * 128 + (quad * 4 + r) * 8 + (lrow & 7)] = f2bf(og);
                }
            }
            __asm__ volatile("s_waitcnt lgkmcnt(0)" ::: "memory");

            bf8 ag = *(const bf8*)&Pw[quad * 128 + lrow * 8];
            #pragma unroll
            for (int n8 = 0; n8 < 8; n8++) {
                bf8 woB = *(const bf8*)(Wo + (size_t)(n8 * 16 + lrow) * 128 + h * D + quad * 8);
                outacc[n8] = __builtin_amdgcn_mfma_f32_16x16x32_bf16(ag, woB, outacc[n8], 0, 0, 0);
            }
        }
        __syncthreads();   // protect Kf/Vf/Qf before next head
    }

    // ---------- epilogue: out = outacc + bo ----------
    #pragma unroll
    for (int n8 = 0; n8 < 8; n8++) {
        int col = n8 * 16 + lrow;
        float bias = bo[col];
        #pragma unroll
        for (int r = 0; r < 4; r++) {
            int q = qc * 16 + quad * 4 + r;
            out[((size_t)(i * N + q)) * C + col] = outacc[n8][r] + bias;
        }
    }
}

// ---------------------------------------------------------------- launch
extern "C" void kernel_launch(void* const* d_in, const int* in_sizes, int n_in,
                              void* d_out, int out_size, void* d_ws, size_t ws_size,
                              hipStream_t stream)
{
    const float* x    = (const float*)d_in[0];
    const float* mask = (const float*)d_in[1];
    const float* lnw  = (const float*)d_in[2];
    const float* lnb  = (const float*)d_in[3];
    const float* wb   = (const float*)d_in[4];
    const float* wq   = (const float*)d_in[5];
    const float* wk   = (const float*)d_in[6];
    const float* wv   = (const float*)d_in[7];
    const float* wg   = (const float*)d_in[8];
    const float* bg   = (const float*)d_in[9];
    const float* wo   = (const float*)d_in[10];
    const float* bo   = (const float*)d_in[11];
    float* out = (float*)d_out;

    uintptr_t w = (uintptr_t)d_ws;
    ushort* xn    = (ushort*)w; w += (size_t)NP * C * 2;   // 16 MB
    ushort* tri_p = (ushort*)w; w += (size_t)H * NP * 2;   // 0.5 MB
    ushort* Wcat  = (ushort*)w; w += 512 * 128 * 2;        // 128 KB
    ushort* Wb    = (ushort*)w; w += 512 * 2;
    ushort* Wo    = (ushort*)w; w += 128 * 128 * 2;        // 32 KB

    prep_weights<<<256, 256, 0, stream>>>(wq, wk, wv, wg, wb, wo, Wcat, Wb, Wo);
    ln_kernel<<<NP / 4, 256, 0, stream>>>(x, lnw, lnb, xn);
    tri_kernel<<<NP / 256, 256, 0, stream>>>(xn, Wb, tri_p);
    fused_attn<<<dim3(N, 4), 256, 0, stream>>>(xn, Wcat, bg, Wo, bo, tri_p, mask, out);
}

// Round 8
// 191.150 us; speedup vs baseline: 1.7393x; 1.7393x over previous
//
#include <hip/hip_runtime.h>

#define N 256
#define C 128
#define H 4
#define D 32
#define NP (N*N)            // 65536 pairs
#define LN_EPS 1e-5f
#define LOG2E 1.4426950408889634f

using f32x4 = __attribute__((ext_vector_type(4))) float;
using bf8   = __attribute__((ext_vector_type(8))) short;   // 8 x bf16 (4 VGPRs)

__device__ __forceinline__ float bf2f(ushort u) {
    union { uint u; float f; } v; v.u = ((uint)u) << 16; return v.f;
}
__device__ __forceinline__ ushort f2bf(float f) {           // RNE
    union { float f; uint u; } v; v.f = f;
    uint u = v.u;
    u += 0x7fffu + ((u >> 16) & 1u);
    return (ushort)(u >> 16);
}
__device__ __forceinline__ ushort f2bf_trunc(float f) {     // truncate (1 VALU op)
    union { float f; uint u; } v; v.f = f;
    return (ushort)(v.u >> 16);
}

// ---------------------------------------------------------------- weights
// q-scale folds 1/sqrt(D) AND log2e (softmax uses exp2 directly)
__global__ __launch_bounds__(256) void prep_weights(
    const float* __restrict__ wq, const float* __restrict__ wk,
    const float* __restrict__ wv, const float* __restrict__ wg,
    const float* __restrict__ wo,
    ushort* __restrict__ Wcat, ushort* __restrict__ Wo)
{
    int t = blockIdx.x * 256 + threadIdx.x;    // 65536 threads
    const float scale = 0.17677669529663689f * LOG2E;
    float v;
    if (t < 16384)       v = wq[t] * scale;
    else if (t < 32768)  v = wk[t - 16384];
    else if (t < 49152)  v = wv[t - 32768];
    else                 v = wg[t - 49152];
    Wcat[t] = f2bf(v);
    if (t < 16384) Wo[t] = f2bf(wo[t]);
}

// ---------------------------------------------------------------- LN + triangle bias
// One wave per pair p=(q,k). fp32 LN in registers, 4 head-dots via wave
// reduction, writes ONLY tri_p (bf16*LOG2E, permuted to attn fragment layout).
// [verified end-to-end in round 6]
__global__ __launch_bounds__(256) void ln_tri_kernel(
    const float* __restrict__ x, const float* __restrict__ lnw,
    const float* __restrict__ lnb, const float* __restrict__ wb,
    ushort* __restrict__ tri_p)
{
    int wave = threadIdx.x >> 6, lane = threadIdx.x & 63;
    int p = blockIdx.x * 4 + wave;
    const float* xp = x + (size_t)p * C;
    float a0 = xp[lane], a1 = xp[lane + 64];
    float s = a0 + a1, ss = a0 * a0 + a1 * a1;
    #pragma unroll
    for (int m = 1; m < 64; m <<= 1) {
        s  += __shfl_xor(s, m, 64);
        ss += __shfl_xor(ss, m, 64);
    }
    float mean = s * (1.f / 128.f);
    float var  = ss * (1.f / 128.f) - mean * mean;
    float rstd = rsqrtf(var + LN_EPS);
    float v0 = (a0 - mean) * rstd * lnw[lane]      + lnb[lane];
    float v1 = (a1 - mean) * rstd * lnw[lane + 64] + lnb[lane + 64];

    float t[H];
    #pragma unroll
    for (int h = 0; h < H; h++)
        t[h] = v0 * wb[h * C + lane] + v1 * wb[h * C + 64 + lane];
    #pragma unroll
    for (int m = 1; m < 64; m <<= 1) {
        #pragma unroll
        for (int h = 0; h < H; h++) t[h] += __shfl_xor(t[h], m, 64);
    }
    if (lane == 0) {
        int q = p >> 8, k = p & 255;
        int qc = q >> 4, quad = (q >> 2) & 3, r = q & 3;
        int n = k >> 4, lrow = k & 15;
        int ln2 = quad * 16 + lrow;
        int v = n * 4 + r, j = v >> 3, m = v & 7;
        int base = ((qc * 8 + j) * 64 + ln2) * 8 + m;
        #pragma unroll
        for (int h = 0; h < H; h++)
            tri_p[h * 65536 + base] = f2bf(t[h] * LOG2E);
    }
}

// ---------------------------------------------------------------- LN + QKVG projection GEMM
// [65536,512] = LN(x)[65536,128] @ Wcat[512,128]^T. Grid 512, 512 threads
// (8 waves, 32x64 each). A-tile LN'd from fp32 x during staging (16 threads
// per row, shfl reduction), staged ONCE; Bt restaged per nt (Wcat L2-resident,
// coalesced). XOR-swizzled LDS (c8 ^ (row&7)) -> 2-way (free) frag reads.
// nt: 0=q(scaled) 1=k 2=v(-> vbT transposed via Bt) 3=gate(sigmoid+bg).
__global__ __launch_bounds__(512, 4) void proj_ln_gemm(
    const float* __restrict__ x, const float* __restrict__ lnw,
    const float* __restrict__ lnb, const ushort* __restrict__ Wcat,
    const float* __restrict__ bg,
    ushort* __restrict__ qb, ushort* __restrict__ kb,
    ushort* __restrict__ vbT, ushort* __restrict__ gate)
{
    __shared__ ushort At[128 * 128];   // 32 KB, swizzled (LN'd x)
    __shared__ ushort Bt[128 * 128];   // 32 KB, swizzled (per-nt weights / V transpose)
    int mt = blockIdx.x;               // 0..511
    int t  = threadIdx.x;

    // ---- LN + A staging: 2048 16B chunks, 16 consecutive threads per row ----
    #pragma unroll
    for (int ii = 0; ii < 4; ii++) {
        int idx = t + ii * 512;            // 0..2047
        int row = idx >> 4, c8 = idx & 15;
        const float* xr = x + ((size_t)(mt * 128 + row)) * C + c8 * 8;
        float4 f0 = ((const float4*)xr)[0];
        float4 f1 = ((const float4*)xr)[1];
        float s  = f0.x + f0.y + f0.z + f0.w + f1.x + f1.y + f1.z + f1.w;
        float ss = f0.x*f0.x + f0.y*f0.y + f0.z*f0.z + f0.w*f0.w
                 + f1.x*f1.x + f1.y*f1.y + f1.z*f1.z + f1.w*f1.w;
        #pragma unroll
        for (int m = 1; m < 16; m <<= 1) {     // reduce within the row's 16 threads
            s  += __shfl_xor(s, m, 64);
            ss += __shfl_xor(ss, m, 64);
        }
        float mean = s * (1.f / 128.f);
        float var  = ss * (1.f / 128.f) - mean * mean;
        float rstd = rsqrtf(var + LN_EPS);
        float4 w0 = ((const float4*)(lnw + c8 * 8))[0];
        float4 w1 = ((const float4*)(lnw + c8 * 8))[1];
        float4 b0 = ((const float4*)(lnb + c8 * 8))[0];
        float4 b1 = ((const float4*)(lnb + c8 * 8))[1];
        union { ushort us[8]; uint4 v; } r;
        r.us[0] = f2bf((f0.x - mean) * rstd * w0.x + b0.x);
        r.us[1] = f2bf((f0.y - mean) * rstd * w0.y + b0.y);
        r.us[2] = f2bf((f0.z - mean) * rstd * w0.z + b0.z);
        r.us[3] = f2bf((f0.w - mean) * rstd * w0.w + b0.w);
        r.us[4] = f2bf((f1.x - mean) * rstd * w1.x + b1.x);
        r.us[5] = f2bf((f1.y - mean) * rstd * w1.y + b1.y);
        r.us[6] = f2bf((f1.z - mean) * rstd * w1.z + b1.z);
        r.us[7] = f2bf((f1.w - mean) * rstd * w1.w + b1.w);
        ((uint4*)At)[row * 16 + (c8 ^ (row & 7))] = r.v;
    }

    int wave = t >> 6, lane = t & 63;
    int lrow = lane & 15, quad = lane >> 4;
    int wr = wave >> 1, wc = wave & 1;           // wr: 32-row strip, wc: 64-col strip
    int i_row = mt >> 1;

    #pragma unroll 1
    for (int nt = 0; nt < 4; nt++) {
        __syncthreads();                 // At ready / prior Bt readers done
        const uint4* Bg = (const uint4*)(Wcat + (size_t)nt * 128 * C);
        #pragma unroll
        for (int ii = 0; ii < 4; ii++) {
            int idx = t + ii * 512;
            int row = idx >> 4, c8 = idx & 15;
            ((uint4*)Bt)[row * 16 + (c8 ^ (row & 7))] = Bg[idx];
        }
        __syncthreads();

        f32x4 acc[2][4];
        #pragma unroll
        for (int mi = 0; mi < 2; mi++)
            #pragma unroll
            for (int ni = 0; ni < 4; ni++) acc[mi][ni] = (f32x4){0.f, 0.f, 0.f, 0.f};

        #pragma unroll
        for (int ks = 0; ks < 4; ks++) {
            int c8 = ks * 4 + quad;
            bf8 a[2], b[4];
            #pragma unroll
            for (int mi = 0; mi < 2; mi++) {
                int row = wr * 32 + mi * 16 + lrow;
                a[mi] = *(const bf8*)&At[(row * 16 + (c8 ^ (row & 7))) * 8];
            }
            #pragma unroll
            for (int ni = 0; ni < 4; ni++) {
                int row = wc * 64 + ni * 16 + lrow;
                b[ni] = *(const bf8*)&Bt[(row * 16 + (c8 ^ (row & 7))) * 8];
            }
            #pragma unroll
            for (int mi = 0; mi < 2; mi++)
                #pragma unroll
                for (int ni = 0; ni < 4; ni++)
                    acc[mi][ni] = __builtin_amdgcn_mfma_f32_16x16x32_bf16(a[mi], b[ni], acc[mi][ni], 0, 0, 0);
        }

        if (nt == 2) {
            // transpose through Bt (done with B reads), then coalesced 16B vbT stores
            __syncthreads();
            #pragma unroll
            for (int mi = 0; mi < 2; mi++) {
                #pragma unroll
                for (int ni = 0; ni < 4; ni++) {
                    int col = wc * 64 + ni * 16 + lrow;            // h*D+d, 0..127
                    #pragma unroll
                    for (int r = 0; r < 4; r++) {
                        int keyl = wr * 32 + mi * 16 + quad * 4 + r;   // 0..127
                        Bt[col * 128 + (keyl ^ (lrow << 3))] = f2bf(acc[mi][ni][r]);
                    }
                }
            }
            __syncthreads();
            #pragma unroll
            for (int itr = 0; itr < 4; itr++) {
                int oidx = itr * 512 + t;          // 0..2047
                int col = oidx >> 4, kc = oidx & 15;
                bf8 val = *(const bf8*)&Bt[col * 128 + ((kc * 8) ^ ((col & 15) << 3))];
                *(bf8*)&vbT[(size_t)(i_row * 128 + col) * N + (mt & 1) * 128 + kc * 8] = val;
            }
        } else {
            ushort* dst = (nt == 0) ? qb : (nt == 1) ? kb : gate;
            bool gated = (nt == 3);
            #pragma unroll
            for (int mi = 0; mi < 2; mi++) {
                #pragma unroll
                for (int ni = 0; ni < 4; ni++) {
                    int col = wc * 64 + ni * 16 + lrow;
                    #pragma unroll
                    for (int r = 0; r < 4; r++) {
                        int row = mt * 128 + wr * 32 + mi * 16 + quad * 4 + r;
                        float v = acc[mi][ni][r];
                        if (gated) v = 1.f / (1.f + __expf(-(v + bg[col])));
                        dst[(size_t)row * C + col] = f2bf(v);
                    }
                }
            }
        }
    }
}

// ---------------------------------------------------------------- attention
// grid (i=256, h=4), 512 threads = 8 waves, 2 q-chunks (16 rows) per wave.
// K/V staged coalesced into LDS in exact MFMA fragment order (conflict-free
// b128 reads). P per wave = one 128-key half (4 KB), flash-style two passes,
// O accumulated unnormalized. LDS = 64 KB -> 2 blocks/CU, 16 waves/CU.
// [verified rounds 4/5]
__global__ __launch_bounds__(512, 4) void attn_kernel(
    const ushort* __restrict__ qb, const ushort* __restrict__ kb,
    const ushort* __restrict__ vbT, const ushort* __restrict__ tri_p,
    const float* __restrict__ mask, ushort* __restrict__ ob)
{
    __shared__ ushort Kf[8192];       // 16 KB: chunk c = kn*64+lane, 8 ushorts each
    __shared__ ushort Vf[8192];       // 16 KB: chunk c = nv*512+ks*64+lane, XOR-swizzled
    __shared__ ushort Pf[8][2048];    // 32 KB: per-wave 128-key half, A-frag order

    int i  = blockIdx.x;
    int h  = blockIdx.y;
    int t  = threadIdx.x;
    int wave = t >> 6, lane = t & 63;
    int lrow = lane & 15, quad = lane >> 4;

    // ---- stage K: global row-major (key, d) -> frag order, coalesced
    {
        const ushort* kt = kb + (size_t)(i * N) * C + h * D;
        #pragma unroll
        for (int it = 0; it < 2; it++) {
            int idx = it * 512 + t;                  // 0..1023
            int key = idx >> 2, d0 = (idx & 3) * 8;
            bf8 kv = *(const bf8*)(kt + (size_t)key * C + d0);
            int c = (idx >> 6) * 64 + (idx & 3) * 16 + ((idx >> 2) & 15);
            *(bf8*)&Kf[c * 8] = kv;
        }
    }
    // ---- stage V: vbT tile is contiguous 16 KB, coalesced; swizzled chunks
    {
        const ushort* vt = vbT + (size_t)((i * H + h) * D) * N;
        #pragma unroll
        for (int it = 0; it < 2; it++) {
            int idx = it * 512 + t;                  // 0..1023
            bf8 vv = *(const bf8*)(vt + idx * 8);
            int c = (idx >> 9) * 512 + ((idx >> 2) & 7) * 64 + (idx & 3) * 16 + ((idx >> 5) & 15);
            c ^= (c >> 6) & 7;
            *(bf8*)&Vf[c * 8] = vv;
        }
    }
    // mask bias per lane's 16 key-columns (log2e-folded)
    float mb[16];
    #pragma unroll
    for (int n = 0; n < 16; n++)
        mb[n] = (1e9f * LOG2E) * (mask[i * N + n * 16 + lrow] - 1.0f);
    __syncthreads();

    ushort* Pw = &Pf[wave][0];
    const ushort* trih = tri_p + (size_t)h * 65536;
    int pq = quad * 32 + (lrow & 7);       // P-write lane-invariant part
    int l3 = (lrow >> 3) & 1;

    #pragma unroll 1
    for (int cc = 0; cc < 2; cc++) {
        int qc = wave * 2 + cc;            // 0..15
        bf8 aq = *(const bf8*)(qb + (size_t)(i * N + qc * 16 + lrow) * C + h * D + quad * 8);
        float sum[4] = {0.f, 0.f, 0.f, 0.f};
        f32x4 o[2];
        o[0] = (f32x4){0.f, 0.f, 0.f, 0.f};
        o[1] = (f32x4){0.f, 0.f, 0.f, 0.f};

        #pragma unroll
        for (int half = 0; half < 2; half++) {
            // ---- S = Q K^T for 128 keys (8 MFMAs, K frags conflict-free from LDS)
            f32x4 s8[8];
            #pragma unroll
            for (int n8 = 0; n8 < 8; n8++) {
                bf8 kf = *(const bf8*)&Kf[((half * 8 + n8) * 64 + lane) * 8];
                s8[n8] = __builtin_amdgcn_mfma_f32_16x16x32_bf16(
                    aq, kf, (f32x4){0.f, 0.f, 0.f, 0.f}, 0, 0, 0);
            }
            // tri bias fragments: 4 x 16B coalesced loads (pre-permuted layout)
            const ushort* tp = trih + ((size_t)(qc * 8 + half * 4) * 64 + lane) * 8;
            bf8 tf[4];
            #pragma unroll
            for (int jj = 0; jj < 4; jj++)
                tf[jj] = *(const bf8*)(tp + jj * 512);

            // ---- exp2 softmax (no max-sub; logits tiny) + P write (A-frag order)
            #pragma unroll
            for (int n8 = 0; n8 < 8; n8++) {
                int pa = (n8 >> 1) * 512 + (((n8 << 1) + l3) & 3) * 128 + pq;
                #pragma unroll
                for (int r = 0; r < 4; r++) {
                    float tb = bf2f(((const ushort*)&tf[n8 >> 1])[((n8 & 1) << 2) + r]);
                    float e  = exp2f(s8[n8][r] + tb + mb[half * 8 + n8]);
                    sum[r]  += e;
                    Pw[pa + r * 8] = f2bf_trunc(e);
                }
            }
            // drain wave-private P writes (also guarantees prior P reads done)
            __asm__ volatile("s_waitcnt lgkmcnt(0)" ::: "memory");

            // ---- O += P V_half (K-dim 128 = 4 ks steps)
            #pragma unroll
            for (int ks = 0; ks < 4; ks++) {
                bf8 ap = *(const bf8*)&Pw[(ks * 64 + lane) * 8];
                int ksg = half * 4 + ks;
                #pragma unroll
                for (int nv = 0; nv < 2; nv++) {
                    int c = nv * 512 + ksg * 64 + (lane ^ (ksg & 7));
                    bf8 bv = *(const bf8*)&Vf[c * 8];
                    o[nv] = __builtin_amdgcn_mfma_f32_16x16x32_bf16(ap, bv, o[nv], 0, 0, 0);
                }
            }
        }
        // row sums -> 1/sum, normalize at epilogue
        #pragma unroll
        for (int r = 0; r < 4; r++) {
            float s = sum[r];
            s += __shfl_xor(s, 1, 64);
            s += __shfl_xor(s, 2, 64);
            s += __shfl_xor(s, 4, 64);
            s += __shfl_xor(s, 8, 64);
            sum[r] = 1.f / s;
        }
        #pragma unroll
        for (int nv = 0; nv < 2; nv++) {
            int d = nv * 16 + lrow;
            #pragma unroll
            for (int r = 0; r < 4; r++) {
                int qg = qc * 16 + quad * 4 + r;
                ob[(size_t)(i * N + qg) * C + h * D + d] = f2bf(o[nv][r] * sum[r]);
            }
        }
    }
}

// ---------------------------------------------------------------- gating + output proj
// out[65536,128] = (O .* gate)[65536,128] @ Wo[128,128]^T + b_o.
// 512 threads, 128x128 tile, XOR-swizzled LDS. [verified round 5]
__global__ __launch_bounds__(512, 4) void out_gemm(
    const ushort* __restrict__ ob, const ushort* __restrict__ gate,
    const ushort* __restrict__ Wo, const float* __restrict__ bo,
    float* __restrict__ out)
{
    __shared__ ushort At[128 * 128];   // 32 KB, swizzled (gated O)
    __shared__ ushort Bt[128 * 128];   // 32 KB, swizzled (Wo)
    int mt = blockIdx.x;               // 0..511
    int t  = threadIdx.x;

    const uint4* Og = (const uint4*)(ob   + (size_t)mt * 128 * C);
    const uint4* Gg = (const uint4*)(gate + (size_t)mt * 128 * C);
    const uint4* Bg = (const uint4*)Wo;
    #pragma unroll
    for (int ii = 0; ii < 4; ii++) {
        int idx = t + ii * 512;                  // 0..2047 chunks
        int row = idx >> 4, c8 = idx & 15;
        int sc = row * 16 + (c8 ^ (row & 7));
        uint4 o4 = Og[idx], g4 = Gg[idx], r4;
        const ushort* os = (const ushort*)&o4;
        const ushort* gs = (const ushort*)&g4;
        ushort* rs = (ushort*)&r4;
        #pragma unroll
        for (int j = 0; j < 8; j++) rs[j] = f2bf(bf2f(os[j]) * bf2f(gs[j]));
        ((uint4*)At)[sc] = r4;
        ((uint4*)Bt)[sc] = Bg[idx];
    }
    __syncthreads();

    int wave = t >> 6, lane = t & 63;
    int lrow = lane & 15, quad = lane >> 4;
    int wr = wave >> 1, wc = wave & 1;

    f32x4 acc[2][4];
    #pragma unroll
    for (int mi = 0; mi < 2; mi++)
        #pragma unroll
        for (int ni = 0; ni < 4; ni++) acc[mi][ni] = (f32x4){0.f, 0.f, 0.f, 0.f};

    #pragma unroll
    for (int ks = 0; ks < 4; ks++) {
        int c8 = ks * 4 + quad;
        bf8 a[2], b[4];
        #pragma unroll
        for (int mi = 0; mi < 2; mi++) {
            int row = wr * 32 + mi * 16 + lrow;
            a[mi] = *(const bf8*)&At[(row * 16 + (c8 ^ (row & 7))) * 8];
        }
        #pragma unroll
        for (int ni = 0; ni < 4; ni++) {
            int row = wc * 64 + ni * 16 + lrow;
            b[ni] = *(const bf8*)&Bt[(row * 16 + (c8 ^ (row & 7))) * 8];
        }
        #pragma unroll
        for (int mi = 0; mi < 2; mi++)
            #pragma unroll
            for (int ni = 0; ni < 4; ni++)
                acc[mi][ni] = __builtin_amdgcn_mfma_f32_16x16x32_bf16(a[mi], b[ni], acc[mi][ni], 0, 0, 0);
    }

    #pragma unroll
    for (int mi = 0; mi < 2; mi++) {
        #pragma unroll
        for (int ni = 0; ni < 4; ni++) {
            int col = wc * 64 + ni * 16 + lrow;   // 0..127
            float bias = bo[col];
            #pragma unroll
            for (int r = 0; r < 4; r++) {
                int row = mt * 128 + wr * 32 + mi * 16 + quad * 4 + r;
                out[(size_t)row * C + col] = acc[mi][ni][r] + bias;
            }
        }
    }
}

// ---------------------------------------------------------------- launch
extern "C" void kernel_launch(void* const* d_in, const int* in_sizes, int n_in,
                              void* d_out, int out_size, void* d_ws, size_t ws_size,
                              hipStream_t stream)
{
    const float* x    = (const float*)d_in[0];
    const float* mask = (const float*)d_in[1];
    const float* lnw  = (const float*)d_in[2];
    const float* lnb  = (const float*)d_in[3];
    const float* wb   = (const float*)d_in[4];
    const float* wq   = (const float*)d_in[5];
    const float* wk   = (const float*)d_in[6];
    const float* wv   = (const float*)d_in[7];
    const float* wg   = (const float*)d_in[8];
    const float* bg   = (const float*)d_in[9];
    const float* wo   = (const float*)d_in[10];
    const float* bo   = (const float*)d_in[11];
    float* out = (float*)d_out;

    uintptr_t w = (uintptr_t)d_ws;
    ushort* qb    = (ushort*)w; w += (size_t)NP * C * 2;   // 16 MB
    ushort* kb    = (ushort*)w; w += (size_t)NP * C * 2;   // 16 MB
    ushort* vbT   = (ushort*)w; w += (size_t)NP * C * 2;   // 16 MB (transposed V)
    ushort* gate  = (ushort*)w; w += (size_t)NP * C * 2;   // 16 MB
    ushort* ob    = (ushort*)w; w += (size_t)NP * C * 2;   // 16 MB
    ushort* tri_p = (ushort*)w; w += (size_t)H * NP * 2;   // 0.5 MB
    ushort* Wcat  = (ushort*)w; w += 512 * 128 * 2;        // 128 KB
    ushort* Wo    = (ushort*)w; w += 128 * 128 * 2;        // 32 KB

    prep_weights<<<256, 256, 0, stream>>>(wq, wk, wv, wg, wo, Wcat, Wo);
    ln_tri_kernel<<<NP / 4, 256, 0, stream>>>(x, lnw, lnb, wb, tri_p);
    proj_ln_gemm<<<512, 512, 0, stream>>>(x, lnw, lnb, Wcat, bg, qb, kb, vbT, gate);
    attn_kernel<<<dim3(N, H), 512, 0, stream>>>(qb, kb, vbT, tri_p, mask, ob);
    out_gemm<<<NP / 128, 512, 0, stream>>>(ob, gate, Wo, bo, out);
}